// Round 9
// baseline (157.548 us; speedup 1.0000x reference)
//
#include <hip/hip_runtime.h>

#define NPF 16
#define NH 8
#define NV 16
#define NN 900
#define ND 256
#define NB 4
#define NM (NN * NN)          // 810000
#define NBINS 512
#define LOG2E 1.44269504088896340736f

// ==================== Kernel L: build PWL LUT of g_h(x) ====================
// lut[h*NBINS + bin] = (g_h(bin/NBINS), g_h((bin+1)/NBINS) - g_h(bin/NBINS))
// g_h(x) = proj_b[h] + sum_k W[h,2k]*sin(x*t_k) + W[h,2k+1]*cos(x*t_k)
__global__ __launch_bounds__(256) void hough_lut(
    const float* __restrict__ proj_w,
    const float* __restrict__ proj_b,
    float2* __restrict__ lut)
{
    const float invt[8] = {100.0f, 31.622776601683793f, 10.0f, 3.1622776601683795f,
                           1.0f, 0.31622776601683794f, 0.1f, 0.031622776601683791f};
    for (int i = threadIdx.x; i < NH * NBINS; i += 256) {
        int h   = i / NBINS;
        int bin = i - h * NBINS;
        float x0 = (float)bin * (1.0f / NBINS);
        float x1 = (float)(bin + 1) * (1.0f / NBINS);
        float g0 = proj_b[h], g1 = proj_b[h];
#pragma unroll
        for (int k = 0; k < 8; k++) {
            float ws = proj_w[h * NPF + 2 * k];
            float wc = proj_w[h * NPF + 2 * k + 1];
            float a0 = x0 * invt[k], a1 = x1 * invt[k];
            g0 = fmaf(ws, __sinf(a0), fmaf(wc, __cosf(a0), g0));
            g1 = fmaf(ws, __sinf(a1), fmaf(wc, __cosf(a1), g1));
        }
        lut[i] = make_float2(g0, g1 - g0);
    }
}

// ============================ Main fused kernel ============================
__global__ __launch_bounds__(256) void hough_fused(
    const float* __restrict__ queries,
    const float* __restrict__ cur_ref,
    const float* __restrict__ vote_w,
    const float* __restrict__ vote_b,
    const float2* __restrict__ lut,
    float* __restrict__ out)
{
    __shared__ __align__(16) float qs[ND];
    __shared__ float part[256];
    __shared__ float vp[NV * 2];
    __shared__ float s2i[NV];
    __shared__ __align__(16) float4 sCoef[NV];
    __shared__ float red[4];
    __shared__ float s_inv;
    __shared__ __align__(16) float2 sLut[NH * NBINS];   // 32 KB

    const int tid = threadIdx.x;
    const int bn  = blockIdx.x;
    const int b   = bn / NN;
    const int n   = bn - b * NN;

    // ---- stage LUT (2048 float4) + query row ----
#pragma unroll
    for (int j = 0; j < 8; j++)
        ((float4*)sLut)[tid + 256 * j] = ((const float4*)lut)[tid + 256 * j];
    qs[tid] = queries[(size_t)bn * ND + tid];
    __syncthreads();

    // ---- votes: 32 outputs, 8 threads each over D=256 ----
    {
        const int o     = tid & 31;
        const int chunk = tid >> 5;
        const float4* wv = (const float4*)(vote_w + o * ND + chunk * 32);
        const float4* qv = (const float4*)(qs + chunk * 32);
        float p = 0.f;
#pragma unroll
        for (int j = 0; j < 8; j++) {
            float4 w4 = wv[j];
            float4 q4 = qv[j];
            p += w4.x * q4.x + w4.y * q4.y + w4.z * q4.z + w4.w * q4.w;
        }
        part[tid] = p;
    }
    __syncthreads();

    if (tid < 32) {
        float s = vote_b[tid];
#pragma unroll
        for (int c = 0; c < 8; c++) s += part[c * 32 + tid];
        vp[tid] = s + cur_ref[((size_t)b * NN + n) * 4 + (tid & 1)];
    } else if (tid >= 64 && tid < 64 + NV) {
        // sigma quirk: sigma_flat[b, i] = sigma[b, i % N], i = n*V + v
        int v = tid - 64;
        int j = (n * NV + v) % NN;
        float c2 = cur_ref[((size_t)b * NN + j) * 4 + 2];
        float c3 = cur_ref[((size_t)b * NN + j) * 4 + 3];
        float sg = (c2 + c3) * 0.25f;   // mean(c2,c3)/2
        s2i[v] = 0.5f / (sg * sg);
    }
    __syncthreads();

    // fold (with log2e pre-scaled): exponent2(m,v) = min(C0 + Ax*cx + Ay*cy + nS*cc, 0)
    if (tid < NV) {
        float x  = vp[2 * tid];
        float y  = vp[2 * tid + 1];
        float s2 = s2i[tid] * LOG2E;
        sCoef[tid] = make_float4(2.f * s2 * x, 2.f * s2 * y,
                                 -s2 * (x * x + y * y), -s2);
    }
    __syncthreads();

    // ---- imap: per-thread m = tid + 256*i ----
    float acc[4] = {0.f, 0.f, 0.f, 0.f};
    const float4* cr4 = (const float4*)cur_ref + (size_t)b * NN;

#pragma unroll 1
    for (int c = 0; c < 2; c++) {
        float ax[8], ay[8], c0[8], ns[8];
#pragma unroll
        for (int v = 0; v < 8; v++) {
            float4 f = sCoef[c * 8 + v];   // LDS broadcast
            ax[v] = f.x; ay[v] = f.y; c0[v] = f.z; ns[v] = f.w;
        }
#pragma unroll
        for (int i = 0; i < 4; i++) {
            int m = tid + 256 * i;
            if (m < NN) {
                float4 cr = cr4[m];
                float cx = cr.x, cy = cr.y;
                float cc = cx * cx + cy * cy;
                float a = 0.f;
#pragma unroll
                for (int v = 0; v < 8; v++) {
                    float t = fmaf(ax[v], cx, c0[v]);
                    t = fmaf(ay[v], cy, t);
                    t = fmaf(ns[v], cc, t);
                    a += exp2f(fminf(t, 0.f));   // native v_exp_f32
                }
                acc[i] += a;
            }
        }
    }

    // ---- block reduce (acc >= 0, |.| redundant) ----
    float lsum = acc[0] + acc[1] + acc[2] + acc[3];
#pragma unroll
    for (int off = 32; off > 0; off >>= 1) lsum += __shfl_down(lsum, off, 64);
    if ((tid & 63) == 0) red[tid >> 6] = lsum;
    __syncthreads();
    if (tid == 0)
        s_inv = 1.0f / fmaxf(red[0] + red[1] + red[2] + red[3], 1e-12f);
    __syncthreads();
    const float inv = s_inv;

    // ---- epilogue: PWL LUT gather + relu + store ----
    float* outrow = out + ((size_t)(b * NH) * NN + n) * NN;
#pragma unroll
    for (int i = 0; i < 4; i++) {
        int m = tid + 256 * i;
        if (m < NN) {
            float x = 1.0f - acc[i] * inv;                      // x in [0,1]
            float t = fminf(fmaxf(x * (float)NBINS, 0.f), (float)NBINS - 0.001f);
            int   ib = (int)t;
            float fr = t - (float)ib;
            float* op = outrow + m;
#pragma unroll
            for (int h = 0; h < NH; h++) {
                float2 vs = sLut[h * NBINS + ib];               // ds_read_b64 gather
                op[(size_t)h * NM] = fmaxf(fmaf(vs.y, fr, vs.x), 0.f);
            }
        }
    }
}

extern "C" void kernel_launch(void* const* d_in, const int* in_sizes, int n_in,
                              void* d_out, int out_size, void* d_ws, size_t ws_size,
                              hipStream_t stream) {
    const float* queries = (const float*)d_in[0];
    const float* cur_ref = (const float*)d_in[1];
    // d_in[2] = prev_ref_points: unused by the reference
    const float* vote_w  = (const float*)d_in[3];
    const float* vote_b  = (const float*)d_in[4];
    const float* proj_w  = (const float*)d_in[5];
    const float* proj_b  = (const float*)d_in[6];
    float* out = (float*)d_out;
    float2* lut = (float2*)d_ws;    // NH*NBINS float2 = 32 KB

    hough_lut<<<1, 256, 0, stream>>>(proj_w, proj_b, lut);
    hough_fused<<<NB * NN, 256, 0, stream>>>(queries, cur_ref, vote_w, vote_b,
                                             lut, out);
}